// Round 7
// baseline (3726.229 us; speedup 1.0000x reference)
//
#include <hip/hip_runtime.h>
#include <hip/hip_bf16.h>

#define TSTEPS 512
#define NEX 256
#define NIN 128
#define HDIM 256
#define NCOLS 16          // example-columns (16 examples each)
#define NROWBLK 16        // unit-tile blocks per column
#define TAGSTRIDE 16      // u32 per tag slot = 64B (own cache line per producer)

typedef __attribute__((ext_vector_type(8))) short short8;   // 8 bf16 (MFMA A/B frag)
typedef __attribute__((ext_vector_type(4))) float f32x4;    // MFMA C/D frag

__device__ __forceinline__ float sig_(float x) {
    return __builtin_amdgcn_rcpf(1.0f + __builtin_amdgcn_exp2f(-1.44269504f * x));
}
__device__ __forceinline__ float tanh_(float x) {
    return 1.0f - 2.0f * __builtin_amdgcn_rcpf(1.0f + __builtin_amdgcn_exp2f(2.88539008f * x));
}

__global__ void zero_flags(unsigned int* tags, int n) {
    int i = blockIdx.x * blockDim.x + threadIdx.x;
    if (i < n) tags[i] = 0u;
}

// ---------------- real kernel: R6 + 16-step X chunking in LDS ----------------
// 256 blocks = 16 unit-tiles x 16 example-columns. Block b: i=b>>4 -> u0=i*16,
// j=b&15 -> e0=j*16. Lane l: mrow=l&15 -> ex (D col); kg=l>>4 -> units (D rows).
// Per-producer monotone tag slots; publish = 1 relaxed store; poll = lanes 0..15.
// X staged per 16-step chunk into LDS (coalesced 128KB burst, off critical path).
__global__ __launch_bounds__(64, 1) void lstm_persist(
    const float* __restrict__ X,     // [256,128,512]
    const float* __restrict__ Wih,   // [1024,128]
    const float* __restrict__ Whh,   // [1024,256]
    const float* __restrict__ bias,  // [1024]
    float* __restrict__ A,           // [512,256,256]
    float* __restrict__ C,           // [512,256,256]
    unsigned int* __restrict__ tags, // [16 cols][16 rowblk][TAGSTRIDE]
    unsigned long long* __restrict__ hbuf) // [2][256][64] u64
{
    __shared__ __align__(16) __hip_bfloat16 Ws[4][16][392];  // weights, 50.2 KB
    __shared__ __align__(16) __hip_bfloat16 Xc[16][17][136]; // x chunk [ex][t&15][ii], 74 KB

    const int tid = threadIdx.x;
    const int b = blockIdx.x;
    const int i = b >> 4, j = b & 15;
    const int u0 = i * 16, e0 = j * 16;

    // ---- one-time weight staging: fp32 -> bf16 in LDS, [gate][unit_local][k] ----
    for (int idx = tid; idx < 64 * 96; idx += 64) {
        const int row = idx / 96, q = idx - row * 96;
        const int g = row >> 4, ul = row & 15;
        float4 v;
        int k0;
        if (q < 64) {
            v = *(const float4*)(Whh + (size_t)(g * HDIM + u0 + ul) * HDIM + 4 * q);
            k0 = 4 * q;
        } else {
            v = *(const float4*)(Wih + (size_t)(g * HDIM + u0 + ul) * NIN + 4 * (q - 64));
            k0 = HDIM + 4 * (q - 64);
        }
        Ws[g][ul][k0 + 0] = (__hip_bfloat16)v.x;
        Ws[g][ul][k0 + 1] = (__hip_bfloat16)v.y;
        Ws[g][ul][k0 + 2] = (__hip_bfloat16)v.z;
        Ws[g][ul][k0 + 3] = (__hip_bfloat16)v.w;
    }
    __syncthreads();

    const int mrow = tid & 15;          // D col -> ex_local
    const int kg   = tid >> 4;          // D rows (kg*4+r) -> unit_local
    const int ex   = e0 + mrow;
    const int ub   = u0 + kg * 4;

    short8 wf0[12], wf1[12], wf2[12], wf3[12];
#pragma unroll
    for (int kk = 0; kk < 12; ++kk) {
        wf0[kk] = *(const short8*)&Ws[0][mrow][kk * 32 + kg * 8];
        wf1[kk] = *(const short8*)&Ws[1][mrow][kk * 32 + kg * 8];
        wf2[kk] = *(const short8*)&Ws[2][mrow][kk * 32 + kg * 8];
        wf3[kk] = *(const short8*)&Ws[3][mrow][kk * 32 + kg * 8];
    }
    float bsr[4][4];
#pragma unroll
    for (int g = 0; g < 4; ++g)
#pragma unroll
        for (int r = 0; r < 4; ++r)
            bsr[g][r] = 2.0f * bias[g * HDIM + ub + r];

    const f32x4 Z4 = {0.f, 0.f, 0.f, 0.f};
    float cr[4] = {0.f, 0.f, 0.f, 0.f};
    f32x4 xa0, xa1, xa2, xa3;

    const unsigned int* tagbase = tags + (size_t)j * NROWBLK * TAGSTRIDE;
    unsigned int* tagself = tags + ((size_t)j * NROWBLK + i) * TAGSTRIDE;

    // Fill LDS x-chunk for steps [t0, t0+16): coalesced (16 consecutive t = 64B line).
#define X_FILL(t0)                                                                 \
    {                                                                              \
        _Pragma("unroll 4")                                                        \
        for (int s = 0; s < 128; ++s) {                                            \
            const int idx = s * 64 + tid;                                          \
            const int tq = idx & 3, row = idx >> 2;                                \
            const int exl = row >> 7, ii = row & 127;                              \
            const float4 v = *(const float4*)(X +                                  \
                ((size_t)(e0 + exl) * NIN + ii) * TSTEPS + (t0) + tq * 4);         \
            Xc[exl][tq * 4 + 0][ii] = (__hip_bfloat16)v.x;                         \
            Xc[exl][tq * 4 + 1][ii] = (__hip_bfloat16)v.y;                         \
            Xc[exl][tq * 4 + 2][ii] = (__hip_bfloat16)v.z;                         \
            Xc[exl][tq * 4 + 3][ii] = (__hip_bfloat16)v.w;                         \
        }                                                                          \
    }

    // Pre-multiply x(tt) into xacc from the LDS chunk (4 ds_read_b128 + 16 MFMA).
#define X_WINDOW(tt)                                                               \
    {                                                                              \
        const int ttl = (tt) & 15;                                                 \
        xa0 = Z4; xa1 = Z4; xa2 = Z4; xa3 = Z4;                                    \
        _Pragma("unroll")                                                          \
        for (int kk = 0; kk < 4; ++kk) {                                           \
            const short8 zf = *(const short8*)&Xc[mrow][ttl][kk * 32 + kg * 8];    \
            xa0 = __builtin_amdgcn_mfma_f32_16x16x32_bf16(wf0[8 + kk], zf, xa0, 0, 0, 0); \
            xa1 = __builtin_amdgcn_mfma_f32_16x16x32_bf16(wf1[8 + kk], zf, xa1, 0, 0, 0); \
            xa2 = __builtin_amdgcn_mfma_f32_16x16x32_bf16(wf2[8 + kk], zf, xa2, 0, 0, 0); \
            xa3 = __builtin_amdgcn_mfma_f32_16x16x32_bf16(wf3[8 + kk], zf, xa3, 0, 0, 0); \
        }                                                                          \
    }

    X_FILL(0);
    X_WINDOW(0);

    for (int t = 0; t < TSTEPS; ++t) {
        f32x4 a0 = xa0, a1 = xa1, a2 = xa2, a3 = xa3;

        if (t > 0) {
            int ready;
            do {
                int v = 0x7fffffff;
                if (tid < NROWBLK)
                    v = (int)__hip_atomic_load(tagbase + tid * TAGSTRIDE,
                                               __ATOMIC_RELAXED, __HIP_MEMORY_SCOPE_AGENT);
                ready = __all(v >= t);
            } while (!ready);
            asm volatile("" ::: "memory");

            const unsigned long long* hb =
                hbuf + (size_t)((t - 1) & 1) * NEX * 64 + (size_t)ex * 64 + kg * 2;
            short8 zh[8];
#pragma unroll
            for (int kk = 0; kk < 8; ++kk) {
                union { unsigned long long u[2]; short8 v; } tmp;
                tmp.u[0] = __hip_atomic_load(hb + kk * 8 + 0, __ATOMIC_RELAXED, __HIP_MEMORY_SCOPE_AGENT);
                tmp.u[1] = __hip_atomic_load(hb + kk * 8 + 1, __ATOMIC_RELAXED, __HIP_MEMORY_SCOPE_AGENT);
                zh[kk] = tmp.v;
            }
#pragma unroll
            for (int kk = 0; kk < 8; ++kk) {
                a0 = __builtin_amdgcn_mfma_f32_16x16x32_bf16(wf0[kk], zh[kk], a0, 0, 0, 0);
                a1 = __builtin_amdgcn_mfma_f32_16x16x32_bf16(wf1[kk], zh[kk], a1, 0, 0, 0);
                a2 = __builtin_amdgcn_mfma_f32_16x16x32_bf16(wf2[kk], zh[kk], a2, 0, 0, 0);
                a3 = __builtin_amdgcn_mfma_f32_16x16x32_bf16(wf3[kk], zh[kk], a3, 0, 0, 0);
            }
        }

        float hr[4];
#pragma unroll
        for (int r = 0; r < 4; ++r) {
            const float gi = sig_(a0[r] + bsr[0][r]);
            const float gf = sig_(a1[r] + bsr[1][r]);
            const float gg = tanh_(a2[r] + bsr[2][r]);
            const float go = sig_(a3[r] + bsr[3][r]);
            cr[r] = gf * cr[r] + gi * gg;
            hr[r] = go * tanh_(cr[r]);
        }

        union { __hip_bfloat16 h[4]; unsigned long long u; } P;
        P.h[0] = __float2bfloat16(hr[0]);
        P.h[1] = __float2bfloat16(hr[1]);
        P.h[2] = __float2bfloat16(hr[2]);
        P.h[3] = __float2bfloat16(hr[3]);
        __hip_atomic_store(hbuf + (size_t)(t & 1) * NEX * 64 + (size_t)ex * 64 + (ub >> 2),
                           P.u, __ATOMIC_RELAXED, __HIP_MEMORY_SCOPE_AGENT);
        asm volatile("s_waitcnt vmcnt(0)" ::: "memory");
        if (tid == 0) {
            __hip_atomic_store(tagself, (unsigned int)(t + 1),
                               __ATOMIC_RELAXED, __HIP_MEMORY_SCOPE_AGENT);
        }

        const size_t off = (size_t)t * NEX * HDIM + (size_t)ex * HDIM + ub;
        *(float4*)&A[off] = make_float4(hr[0], hr[1], hr[2], hr[3]);
        *(float4*)&C[off] = make_float4(cr[0], cr[1], cr[2], cr[3]);

        if (t + 1 < TSTEPS) {
            if (((t + 1) & 15) == 0) X_FILL(t + 1);
            X_WINDOW(t + 1);
        }
    }
#undef X_FILL
#undef X_WINDOW
}

// ---------------- probe: naked sync protocol, same grid/steps ----------------
// Measures the pure per-step cost of: poll(16 tags) -> publish u64 -> vmcnt(0)
// -> tag store. No LDS, no MFMA, no outputs. Next round: read its dur_us vs
// the real kernel's from the rocprof per-dispatch table (+ bench total).
__global__ __launch_bounds__(64, 1) void probe_sync(
    unsigned int* __restrict__ tags,
    unsigned long long* __restrict__ hbuf)
{
    const int tid = threadIdx.x;
    const int b = blockIdx.x;
    const int i = b >> 4, j = b & 15;
    const int mrow = tid & 15, kg = tid >> 4;
    const int ex = j * 16 + mrow;
    const int ub = i * 16 + kg * 4;
    const unsigned int* tagbase = tags + (size_t)j * NROWBLK * TAGSTRIDE;
    unsigned int* tagself = tags + ((size_t)j * NROWBLK + i) * TAGSTRIDE;

    for (int t = 0; t < TSTEPS; ++t) {
        if (t > 0) {
            int ready;
            do {
                int v = 0x7fffffff;
                if (tid < NROWBLK)
                    v = (int)__hip_atomic_load(tagbase + tid * TAGSTRIDE,
                                               __ATOMIC_RELAXED, __HIP_MEMORY_SCOPE_AGENT);
                ready = __all(v >= t);
            } while (!ready);
            asm volatile("" ::: "memory");
        }
        __hip_atomic_store(hbuf + (size_t)(t & 1) * NEX * 64 + (size_t)ex * 64 + (ub >> 2),
                           0ULL, __ATOMIC_RELAXED, __HIP_MEMORY_SCOPE_AGENT);
        asm volatile("s_waitcnt vmcnt(0)" ::: "memory");
        if (tid == 0) {
            __hip_atomic_store(tagself, (unsigned int)(t + 1),
                               __ATOMIC_RELAXED, __HIP_MEMORY_SCOPE_AGENT);
        }
    }
}

extern "C" void kernel_launch(void* const* d_in, const int* in_sizes, int n_in,
                              void* d_out, int out_size, void* d_ws, size_t ws_size,
                              hipStream_t stream) {
    const float* X   = (const float*)d_in[0];
    const float* Wih = (const float*)d_in[1];
    const float* Whh = (const float*)d_in[2];
    const float* b   = (const float*)d_in[3];
    float* A = (float*)d_out;
    float* C = A + (size_t)TSTEPS * NEX * HDIM;

    unsigned int* tags = (unsigned int*)d_ws;           // 256 slots x 64B = 16 KB
    unsigned long long* hbuf =
        (unsigned long long*)((char*)d_ws + (size_t)NCOLS * NROWBLK * TAGSTRIDE * sizeof(unsigned int));

    const int ntags = NCOLS * NROWBLK * TAGSTRIDE;

    // real kernel
    zero_flags<<<(ntags + 255) / 256, 256, 0, stream>>>(tags, ntags);
    {
        void* args[] = {(void*)&X, (void*)&Wih, (void*)&Whh, (void*)&b,
                        (void*)&A, (void*)&C, (void*)&tags, (void*)&hbuf};
        hipError_t err = hipLaunchCooperativeKernel((const void*)lstm_persist,
                                                    dim3(256), dim3(64), args, 0, stream);
        if (err != hipSuccess) {
            lstm_persist<<<dim3(256), dim3(64), 0, stream>>>(X, Wih, Whh, b, A, C, tags, hbuf);
        }
    }

    // probe: naked protocol (reuses tags/hbuf; touches only d_ws)
    zero_flags<<<(ntags + 255) / 256, 256, 0, stream>>>(tags, ntags);
    {
        void* args[] = {(void*)&tags, (void*)&hbuf};
        hipError_t err = hipLaunchCooperativeKernel((const void*)probe_sync,
                                                    dim3(256), dim3(64), args, 0, stream);
        if (err != hipSuccess) {
            probe_sync<<<dim3(256), dim3(64), 0, stream>>>(tags, hbuf);
        }
    }
}

// Round 8
// 1843.493 us; speedup vs baseline: 2.0213x; 2.0213x over previous
//
#include <hip/hip_runtime.h>
#include <hip/hip_bf16.h>

#define TSTEPS 512
#define NEX 256
#define NIN 128
#define HDIM 256
#define NCOLS 16          // example-columns (16 examples each)
#define NROWBLK 16        // unit-tile blocks per column
#define TAGSTRIDE 16      // u32 per tag slot = 64B (own cache line per producer)

typedef __attribute__((ext_vector_type(8))) short short8;   // 8 bf16 (MFMA A/B frag)
typedef __attribute__((ext_vector_type(4))) float f32x4;    // MFMA C/D frag

__device__ __forceinline__ float sig_(float x) {
    return __builtin_amdgcn_rcpf(1.0f + __builtin_amdgcn_exp2f(-1.44269504f * x));
}
__device__ __forceinline__ float tanh_(float x) {
    return 1.0f - 2.0f * __builtin_amdgcn_rcpf(1.0f + __builtin_amdgcn_exp2f(2.88539008f * x));
}

__global__ void zero_flags(unsigned int* tags, int n) {
    int i = blockIdx.x * blockDim.x + threadIdx.x;
    if (i < n) tags[i] = 0u;
}

// ---- one-time X pre-pack: X[ex][ii][t] f32 -> xp[t][ex][o] bf16, o = kg*32+kk*8+e
// (ii = kk*32+kg*8+e), so lane (mrow,kg)'s per-step x = 4 contiguous 16B frags.
// Block = (ex, 16-step chunk). Reads coalesced along t; writes contiguous per t.
__global__ __launch_bounds__(64) void pack_x(const float* __restrict__ X,
                                             unsigned short* __restrict__ xp) {
    __shared__ __align__(16) unsigned short Ls[16][136];
    const int tid = threadIdx.x;
    const int ex = blockIdx.x >> 5;
    const int t0 = (blockIdx.x & 31) * 16;
#pragma unroll
    for (int s = 0; s < 8; ++s) {
        const int idx = s * 64 + tid;          // 512 float4 = 128 ii x 4 tq
        const int ii = idx >> 2, tq = idx & 3;
        const float4 v = *(const float4*)(X + ((size_t)ex * NIN + ii) * TSTEPS + t0 + tq * 4);
        const int o = ((ii >> 3) & 3) * 32 + (ii >> 5) * 8 + (ii & 7);
        __hip_bfloat16 b0 = (__hip_bfloat16)v.x, b1 = (__hip_bfloat16)v.y,
                       b2 = (__hip_bfloat16)v.z, b3 = (__hip_bfloat16)v.w;
        Ls[tq * 4 + 0][o] = *(unsigned short*)&b0;
        Ls[tq * 4 + 1][o] = *(unsigned short*)&b1;
        Ls[tq * 4 + 2][o] = *(unsigned short*)&b2;
        Ls[tq * 4 + 3][o] = *(unsigned short*)&b3;
    }
    __syncthreads();
#pragma unroll
    for (int s = 0; s < 4; ++s) {
        const int idx = s * 64 + tid;          // 256 chunks of 16B
        const int tl = idx >> 4, c = idx & 15;
        const short8 v = *(const short8*)&Ls[tl][c * 8];
        *(short8*)(xp + ((size_t)(t0 + tl) * NEX + ex) * NIN + c * 8) = v;
    }
}

// ---- persistent LSTM: R6 protocol + packed-x shadow path ----
// 256 blocks = 16 unit-tiles x 16 ex-columns. Lane l: mrow=l&15 -> ex (D col);
// kg=l>>4 -> units ub=u0+4kg..+3 (D rows). Per-producer monotone tags (64B apart);
// publish = 1 relaxed agent store, poll = lanes 0..15. h via hbuf parity dbuf (u64).
// x: 4 contiguous plain 16B loads (prefetched pre-poll), pre-multiplied into xa in
// the post-publish shadow -> post-spin path = h-load + 32 MFMA + pointwise + publish.
template<int PX>
__global__ __launch_bounds__(64, 1) void lstm_persist(
    const float* __restrict__ X,     // [256,128,512]
    const float* __restrict__ Wih,   // [1024,128]
    const float* __restrict__ Whh,   // [1024,256]
    const float* __restrict__ bias,  // [1024]
    float* __restrict__ A,           // [512,256,256]
    float* __restrict__ C,           // [512,256,256]
    unsigned int* __restrict__ tags, // [16 cols][16 rowblk][TAGSTRIDE]
    unsigned long long* __restrict__ hbuf,   // [2][256][64] u64
    const unsigned short* __restrict__ xp)   // [512][256][128] packed bf16 frags
{
    __shared__ __align__(16) __hip_bfloat16 Ws[4][16][392];  // weights, 50.2 KB

    const int tid = threadIdx.x;
    const int b = blockIdx.x;
    const int i = b >> 4, j = b & 15;
    const int u0 = i * 16, e0 = j * 16;

    // one-time weight staging: fp32 -> bf16 in LDS, [gate][unit_local][k]
    for (int idx = tid; idx < 64 * 96; idx += 64) {
        const int row = idx / 96, q = idx - row * 96;
        const int g = row >> 4, ul = row & 15;
        float4 v;
        int k0;
        if (q < 64) {
            v = *(const float4*)(Whh + (size_t)(g * HDIM + u0 + ul) * HDIM + 4 * q);
            k0 = 4 * q;
        } else {
            v = *(const float4*)(Wih + (size_t)(g * HDIM + u0 + ul) * NIN + 4 * (q - 64));
            k0 = HDIM + 4 * (q - 64);
        }
        Ws[g][ul][k0 + 0] = (__hip_bfloat16)v.x;
        Ws[g][ul][k0 + 1] = (__hip_bfloat16)v.y;
        Ws[g][ul][k0 + 2] = (__hip_bfloat16)v.z;
        Ws[g][ul][k0 + 3] = (__hip_bfloat16)v.w;
    }
    __syncthreads();

    const int mrow = tid & 15;          // D col -> ex_local
    const int kg   = tid >> 4;          // D rows (kg*4+r) -> unit_local
    const int ex   = e0 + mrow;
    const int ub   = u0 + kg * 4;

    short8 wf0[12], wf1[12], wf2[12], wf3[12];
#pragma unroll
    for (int kk = 0; kk < 12; ++kk) {
        wf0[kk] = *(const short8*)&Ws[0][mrow][kk * 32 + kg * 8];
        wf1[kk] = *(const short8*)&Ws[1][mrow][kk * 32 + kg * 8];
        wf2[kk] = *(const short8*)&Ws[2][mrow][kk * 32 + kg * 8];
        wf3[kk] = *(const short8*)&Ws[3][mrow][kk * 32 + kg * 8];
    }
    float bsr[4][4];
#pragma unroll
    for (int g = 0; g < 4; ++g)
#pragma unroll
        for (int r = 0; r < 4; ++r)
            bsr[g][r] = 2.0f * bias[g * HDIM + ub + r];

    const f32x4 Z4 = {0.f, 0.f, 0.f, 0.f};
    float cr[4] = {0.f, 0.f, 0.f, 0.f};

    const unsigned int* tagbase = tags + (size_t)j * NROWBLK * TAGSTRIDE;
    unsigned int* tagself = tags + ((size_t)j * NROWBLK + i) * TAGSTRIDE;

    // scalar x-gather (fallback path only)
#define X_GATHER(dst, tt)                                                          \
    {                                                                              \
        const float* xb = X + (size_t)ex * NIN * TSTEPS + (tt);                    \
        _Pragma("unroll")                                                          \
        for (int kk = 0; kk < 4; ++kk) {                                           \
            union { __hip_bfloat16 hh[8]; short8 v; } uxx;                         \
            _Pragma("unroll")                                                      \
            for (int e = 0; e < 8; ++e)                                            \
                uxx.hh[e] = (__hip_bfloat16)xb[(size_t)(kk * 32 + kg * 8 + e) * TSTEPS]; \
            (dst)[kk] = uxx.v;                                                     \
        }                                                                          \
    }

    // prologue: x frags + xa for t=0
    short8 xn[4];
    if (PX) {
        const unsigned short* xrow = xp + ((size_t)0 * NEX + ex) * NIN + kg * 32;
#pragma unroll
        for (int kk = 0; kk < 4; ++kk) xn[kk] = *(const short8*)(xrow + kk * 8);
    } else {
        X_GATHER(xn, 0);
    }
    f32x4 xa0 = Z4, xa1 = Z4, xa2 = Z4, xa3 = Z4;
#pragma unroll
    for (int kk = 0; kk < 4; ++kk) {
        xa0 = __builtin_amdgcn_mfma_f32_16x16x32_bf16(wf0[8 + kk], xn[kk], xa0, 0, 0, 0);
        xa1 = __builtin_amdgcn_mfma_f32_16x16x32_bf16(wf1[8 + kk], xn[kk], xa1, 0, 0, 0);
        xa2 = __builtin_amdgcn_mfma_f32_16x16x32_bf16(wf2[8 + kk], xn[kk], xa2, 0, 0, 0);
        xa3 = __builtin_amdgcn_mfma_f32_16x16x32_bf16(wf3[8 + kk], xn[kk], xa3, 0, 0, 0);
    }

    for (int t = 0; t < TSTEPS; ++t) {
        // ---- prefetch x(t+1) frags (plain coalesced loads; drain during spin) ----
        const int tn = (t + 1) & (TSTEPS - 1);
        if (PX) {
            const unsigned short* xrow = xp + ((size_t)tn * NEX + ex) * NIN + kg * 32;
#pragma unroll
            for (int kk = 0; kk < 4; ++kk) xn[kk] = *(const short8*)(xrow + kk * 8);
            asm volatile("" ::: "memory");   // keep the loads issued before the spin
        }

        f32x4 a0 = xa0, a1 = xa1, a2 = xa2, a3 = xa3;

        if (t > 0) {
            // ---- poll: lanes 0..15 each watch one producer's tag line ----
            int ready;
            do {
                int v = 0x7fffffff;
                if (tid < NROWBLK)
                    v = (int)__hip_atomic_load(tagbase + tid * TAGSTRIDE,
                                               __ATOMIC_RELAXED, __HIP_MEMORY_SCOPE_AGENT);
                ready = __all(v >= t);
            } while (!ready);
            asm volatile("" ::: "memory");

            // ---- h[t-1] into B-fragments + 32 h-part MFMAs ----
            const unsigned long long* hb =
                hbuf + (size_t)((t - 1) & 1) * NEX * 64 + (size_t)ex * 64 + kg * 2;
            short8 zh[8];
#pragma unroll
            for (int kk = 0; kk < 8; ++kk) {
                union { unsigned long long u[2]; short8 v; } tmp;
                tmp.u[0] = __hip_atomic_load(hb + kk * 8 + 0, __ATOMIC_RELAXED, __HIP_MEMORY_SCOPE_AGENT);
                tmp.u[1] = __hip_atomic_load(hb + kk * 8 + 1, __ATOMIC_RELAXED, __HIP_MEMORY_SCOPE_AGENT);
                zh[kk] = tmp.v;
            }
#pragma unroll
            for (int kk = 0; kk < 8; ++kk) {
                a0 = __builtin_amdgcn_mfma_f32_16x16x32_bf16(wf0[kk], zh[kk], a0, 0, 0, 0);
                a1 = __builtin_amdgcn_mfma_f32_16x16x32_bf16(wf1[kk], zh[kk], a1, 0, 0, 0);
                a2 = __builtin_amdgcn_mfma_f32_16x16x32_bf16(wf2[kk], zh[kk], a2, 0, 0, 0);
                a3 = __builtin_amdgcn_mfma_f32_16x16x32_bf16(wf3[kk], zh[kk], a3, 0, 0, 0);
            }
        }

        // ---- pointwise cell (register-local) ----
        float hr[4];
#pragma unroll
        for (int r = 0; r < 4; ++r) {
            const float gi = sig_(a0[r] + bsr[0][r]);
            const float gf = sig_(a1[r] + bsr[1][r]);
            const float gg = tanh_(a2[r] + bsr[2][r]);
            const float go = sig_(a3[r] + bsr[3][r]);
            cr[r] = gf * cr[r] + gi * gg;
            hr[r] = go * tanh_(cr[r]);
        }

        // ---- publish h (1 u64 agent store), drain, tag (1 plain agent store) ----
        union { __hip_bfloat16 h[4]; unsigned long long u; } P;
        P.h[0] = __float2bfloat16(hr[0]);
        P.h[1] = __float2bfloat16(hr[1]);
        P.h[2] = __float2bfloat16(hr[2]);
        P.h[3] = __float2bfloat16(hr[3]);
        __hip_atomic_store(hbuf + (size_t)(t & 1) * NEX * 64 + (size_t)ex * 64 + (ub >> 2),
                           P.u, __ATOMIC_RELAXED, __HIP_MEMORY_SCOPE_AGENT);
        asm volatile("s_waitcnt vmcnt(0)" ::: "memory");
        if (tid == 0) {
            __hip_atomic_store(tagself, (unsigned int)(t + 1),
                               __ATOMIC_RELAXED, __HIP_MEMORY_SCOPE_AGENT);
        }

        // ---- shadow work: outputs, fallback x-gather, next-step x MFMAs ----
        const size_t off = (size_t)t * NEX * HDIM + (size_t)ex * HDIM + ub;
        *(float4*)&A[off] = make_float4(hr[0], hr[1], hr[2], hr[3]);
        *(float4*)&C[off] = make_float4(cr[0], cr[1], cr[2], cr[3]);

        if (!PX) {
            X_GATHER(xn, tn);
        }
        xa0 = Z4; xa1 = Z4; xa2 = Z4; xa3 = Z4;
#pragma unroll
        for (int kk = 0; kk < 4; ++kk) {
            xa0 = __builtin_amdgcn_mfma_f32_16x16x32_bf16(wf0[8 + kk], xn[kk], xa0, 0, 0, 0);
            xa1 = __builtin_amdgcn_mfma_f32_16x16x32_bf16(wf1[8 + kk], xn[kk], xa1, 0, 0, 0);
            xa2 = __builtin_amdgcn_mfma_f32_16x16x32_bf16(wf2[8 + kk], xn[kk], xa2, 0, 0, 0);
            xa3 = __builtin_amdgcn_mfma_f32_16x16x32_bf16(wf3[8 + kk], xn[kk], xa3, 0, 0, 0);
        }
    }
#undef X_GATHER
}

extern "C" void kernel_launch(void* const* d_in, const int* in_sizes, int n_in,
                              void* d_out, int out_size, void* d_ws, size_t ws_size,
                              hipStream_t stream) {
    const float* X   = (const float*)d_in[0];
    const float* Wih = (const float*)d_in[1];
    const float* Whh = (const float*)d_in[2];
    const float* b   = (const float*)d_in[3];
    float* A = (float*)d_out;
    float* C = A + (size_t)TSTEPS * NEX * HDIM;

    const size_t tags_bytes = (size_t)NCOLS * NROWBLK * TAGSTRIDE * sizeof(unsigned int); // 16 KB
    const size_t hbuf_bytes = (size_t)2 * NEX * 64 * sizeof(unsigned long long);          // 256 KB
    const size_t xp_bytes   = (size_t)TSTEPS * NEX * NIN * sizeof(unsigned short);        // 32 MB

    unsigned int* tags = (unsigned int*)d_ws;
    unsigned long long* hbuf = (unsigned long long*)((char*)d_ws + tags_bytes);
    unsigned short* xpw = (unsigned short*)((char*)d_ws + tags_bytes + hbuf_bytes);
    const bool px = ws_size >= tags_bytes + hbuf_bytes + xp_bytes;

    const int ntags = NCOLS * NROWBLK * TAGSTRIDE;
    zero_flags<<<(ntags + 255) / 256, 256, 0, stream>>>(tags, ntags);

    if (px) {
        pack_x<<<dim3(NEX * 32), dim3(64), 0, stream>>>(X, xpw);
        const unsigned short* xpc = xpw;
        void* args[] = {(void*)&X, (void*)&Wih, (void*)&Whh, (void*)&b,
                        (void*)&A, (void*)&C, (void*)&tags, (void*)&hbuf, (void*)&xpc};
        hipError_t err = hipLaunchCooperativeKernel((const void*)lstm_persist<1>,
                                                    dim3(256), dim3(64), args, 0, stream);
        if (err != hipSuccess) {
            lstm_persist<1><<<dim3(256), dim3(64), 0, stream>>>(X, Wih, Whh, b, A, C, tags, hbuf, xpc);
        }
    } else {
        const unsigned short* xpc = nullptr;
        void* args[] = {(void*)&X, (void*)&Wih, (void*)&Whh, (void*)&b,
                        (void*)&A, (void*)&C, (void*)&tags, (void*)&hbuf, (void*)&xpc};
        hipError_t err = hipLaunchCooperativeKernel((const void*)lstm_persist<0>,
                                                    dim3(256), dim3(64), args, 0, stream);
        if (err != hipSuccess) {
            lstm_persist<0><<<dim3(256), dim3(64), 0, stream>>>(X, Wih, Whh, b, A, C, tags, hbuf, xpc);
        }
    }
}

// Round 11
// 1132.516 us; speedup vs baseline: 3.2902x; 1.6278x over previous
//
#include <hip/hip_runtime.h>
#include <hip/hip_bf16.h>

#define TSTEPS 512
#define NEX 256
#define NIN 128
#define HDIM 256
#define NCOLS 16
#define NROWBLK 16

typedef __attribute__((ext_vector_type(8))) short short8;   // 8 bf16 (MFMA A/B frag)
typedef __attribute__((ext_vector_type(4))) float f32x4;    // MFMA C/D frag
typedef __attribute__((ext_vector_type(4))) int i32x4;      // VGPR quad for asm payloads

__device__ __forceinline__ float sig_(float x) {
    return __builtin_amdgcn_rcpf(1.0f + __builtin_amdgcn_exp2f(-1.44269504f * x));
}
__device__ __forceinline__ float tanh_(float x) {
    return 1.0f - 2.0f * __builtin_amdgcn_rcpf(1.0f + __builtin_amdgcn_exp2f(2.88539008f * x));
}

__global__ void zero_ws(unsigned int* p, int n) {
    int i = blockIdx.x * blockDim.x + threadIdx.x;
    if (i < n) p[i] = 0u;
}

// one-time X pre-pack (identical to R8, proven): X[ex][ii][t] f32 -> xp[t][ex][o] bf16
__global__ __launch_bounds__(64) void pack_x(const float* __restrict__ X,
                                             unsigned short* __restrict__ xp) {
    __shared__ __align__(16) unsigned short Ls[16][136];
    const int tid = threadIdx.x;
    const int ex = blockIdx.x >> 5;
    const int t0 = (blockIdx.x & 31) * 16;
#pragma unroll
    for (int s = 0; s < 8; ++s) {
        const int idx = s * 64 + tid;
        const int ii = idx >> 2, tq = idx & 3;
        const float4 v = *(const float4*)(X + ((size_t)ex * NIN + ii) * TSTEPS + t0 + tq * 4);
        const int o = ((ii >> 3) & 3) * 32 + (ii >> 5) * 8 + (ii & 7);
        __hip_bfloat16 b0 = (__hip_bfloat16)v.x, b1 = (__hip_bfloat16)v.y,
                       b2 = (__hip_bfloat16)v.z, b3 = (__hip_bfloat16)v.w;
        Ls[tq * 4 + 0][o] = *(unsigned short*)&b0;
        Ls[tq * 4 + 1][o] = *(unsigned short*)&b1;
        Ls[tq * 4 + 2][o] = *(unsigned short*)&b2;
        Ls[tq * 4 + 3][o] = *(unsigned short*)&b3;
    }
    __syncthreads();
#pragma unroll
    for (int s = 0; s < 4; ++s) {
        const int idx = s * 64 + tid;
        const int tl = idx >> 4, c = idx & 15;
        const short8 v = *(const short8*)&Ls[tl][c * 8];
        *(short8*)(xp + ((size_t)(t0 + tl) * NEX + ex) * NIN + c * 8) = v;
    }
}

// Persistent LSTM with fused message protocol.
// 256 blocks = 16 unit-tiles x 16 ex-columns; block b: i=b>>4 (u0=i*16), j=b&15 (e0=j*16).
// Lane l: mrow=l&15 -> ex=e0+mrow (D col); kg=l>>4 -> units ub=u0+4kg..+3 (D rows).
// Message: 16B [h01 | tag | h23 | tag] per producer-lane in hbuf2[t&1][ex][g=i*4+kg].
// Each 8B half is a self-validating (data,flag) packet -> no 128b-atomicity assumption.
// Publish = ONE global_store_dwordx4 sc0 sc1 (no drain, no separate tag store).
// Consumer poll == h-load: 16 dwordx4 sc0 sc1, all 32 tag words must equal t.
// Overwrite-safety: a producer reaches step t+2 (same parity slot) only after observing
// tags >= t+2 from all 16 producers of its column, which requires every consumer to have
// consumed step t. Hang-proof: after 4096 rounds fall back to R8 agent-atomic polling.
template<int PX>
__global__ __launch_bounds__(64, 1) void lstm_persist(
    const float* __restrict__ X,     // [256,128,512]
    const float* __restrict__ Wih,   // [1024,128]
    const float* __restrict__ Whh,   // [1024,256]
    const float* __restrict__ bias,  // [1024]
    float* __restrict__ A,           // [512,256,256]
    float* __restrict__ C,           // [512,256,256]
    char* __restrict__ hbuf2,        // [2][256][64] x 16B messages = 512 KB
    const unsigned short* __restrict__ xp)   // [512][256][128] packed bf16 frags
{
    __shared__ __align__(16) __hip_bfloat16 Ws[4][16][392];  // 50.2 KB

    const int tid = threadIdx.x;
    const int b = blockIdx.x;
    const int i = b >> 4, j = b & 15;
    const int u0 = i * 16, e0 = j * 16;

    // one-time weight staging: fp32 -> bf16 LDS [gate][unit_local][k]
    for (int idx = tid; idx < 64 * 96; idx += 64) {
        const int row = idx / 96, q = idx - row * 96;
        const int g = row >> 4, ul = row & 15;
        float4 v;
        int k0;
        if (q < 64) {
            v = *(const float4*)(Whh + (size_t)(g * HDIM + u0 + ul) * HDIM + 4 * q);
            k0 = 4 * q;
        } else {
            v = *(const float4*)(Wih + (size_t)(g * HDIM + u0 + ul) * NIN + 4 * (q - 64));
            k0 = HDIM + 4 * (q - 64);
        }
        Ws[g][ul][k0 + 0] = (__hip_bfloat16)v.x;
        Ws[g][ul][k0 + 1] = (__hip_bfloat16)v.y;
        Ws[g][ul][k0 + 2] = (__hip_bfloat16)v.z;
        Ws[g][ul][k0 + 3] = (__hip_bfloat16)v.w;
    }
    __syncthreads();

    const int mrow = tid & 15;          // D col -> ex_local
    const int kg   = tid >> 4;          // D rows (kg*4+r) -> unit_local
    const int ex   = e0 + mrow;
    const int ub   = u0 + kg * 4;

    short8 wf0[12], wf1[12], wf2[12], wf3[12];
#pragma unroll
    for (int kk = 0; kk < 12; ++kk) {
        wf0[kk] = *(const short8*)&Ws[0][mrow][kk * 32 + kg * 8];
        wf1[kk] = *(const short8*)&Ws[1][mrow][kk * 32 + kg * 8];
        wf2[kk] = *(const short8*)&Ws[2][mrow][kk * 32 + kg * 8];
        wf3[kk] = *(const short8*)&Ws[3][mrow][kk * 32 + kg * 8];
    }
    float bsr[4][4];
#pragma unroll
    for (int g = 0; g < 4; ++g)
#pragma unroll
        for (int r = 0; r < 4; ++r)
            bsr[g][r] = 2.0f * bias[g * HDIM + ub + r];

    const f32x4 Z4 = {0.f, 0.f, 0.f, 0.f};
    float cr[4] = {0.f, 0.f, 0.f, 0.f};

    // consumer slot base: ex*1024 + kg*32 (+128 per kk); producer slot: ex*1024 + (i*4+kg)*16
    const size_t cons_off = (size_t)ex * 1024 + (size_t)kg * 32;
    const size_t prod_off = (size_t)ex * 1024 + (size_t)(i * 4 + kg) * 16;

#define X_GATHER(dst, tt)                                                          \
    {                                                                              \
        const float* xb = X + (size_t)ex * NIN * TSTEPS + (tt);                    \
        _Pragma("unroll")                                                          \
        for (int kk = 0; kk < 4; ++kk) {                                           \
            union { __hip_bfloat16 hh[8]; short8 v; } uxx;                         \
            _Pragma("unroll")                                                      \
            for (int e = 0; e < 8; ++e)                                            \
                uxx.hh[e] = (__hip_bfloat16)xb[(size_t)(kk * 32 + kg * 8 + e) * TSTEPS]; \
            (dst)[kk] = uxx.v;                                                     \
        }                                                                          \
    }

    for (int t = 0; t < TSTEPS; ++t) {
        // ---- x fragments for this step ----
        short8 xf[4];
        if (PX) {
            const unsigned short* xrow = xp + ((size_t)t * NEX + ex) * NIN + kg * 32;
#pragma unroll
            for (int kk = 0; kk < 4; ++kk) xf[kk] = *(const short8*)(xrow + kk * 8);
        } else {
            X_GATHER(xf, t);
        }

        f32x4 a0 = Z4, a1 = Z4, a2 = Z4, a3 = Z4;

        if (t > 0) {
            const char* sb = hbuf2 + (size_t)((t - 1) & 1) * (NEX * 64 * 16) + cons_off;
            union Msg { i32x4 i4; unsigned int u[4]; } m[16];
            int rounds = 0;
            for (;;) {
                // fused poll + h-load: 16 x 16B messages, one drain
                asm volatile(
                    "global_load_dwordx4 %0, %16, off sc0 sc1\n\t"
                    "global_load_dwordx4 %1, %16, off offset:16 sc0 sc1\n\t"
                    "global_load_dwordx4 %2, %16, off offset:128 sc0 sc1\n\t"
                    "global_load_dwordx4 %3, %16, off offset:144 sc0 sc1\n\t"
                    "global_load_dwordx4 %4, %16, off offset:256 sc0 sc1\n\t"
                    "global_load_dwordx4 %5, %16, off offset:272 sc0 sc1\n\t"
                    "global_load_dwordx4 %6, %16, off offset:384 sc0 sc1\n\t"
                    "global_load_dwordx4 %7, %16, off offset:400 sc0 sc1\n\t"
                    "global_load_dwordx4 %8, %16, off offset:512 sc0 sc1\n\t"
                    "global_load_dwordx4 %9, %16, off offset:528 sc0 sc1\n\t"
                    "global_load_dwordx4 %10, %16, off offset:640 sc0 sc1\n\t"
                    "global_load_dwordx4 %11, %16, off offset:656 sc0 sc1\n\t"
                    "global_load_dwordx4 %12, %16, off offset:768 sc0 sc1\n\t"
                    "global_load_dwordx4 %13, %16, off offset:784 sc0 sc1\n\t"
                    "global_load_dwordx4 %14, %16, off offset:896 sc0 sc1\n\t"
                    "global_load_dwordx4 %15, %16, off offset:912 sc0 sc1\n\t"
                    "s_waitcnt vmcnt(0)"
                    : "=&v"(m[0].i4), "=&v"(m[1].i4), "=&v"(m[2].i4), "=&v"(m[3].i4),
                      "=&v"(m[4].i4), "=&v"(m[5].i4), "=&v"(m[6].i4), "=&v"(m[7].i4),
                      "=&v"(m[8].i4), "=&v"(m[9].i4), "=&v"(m[10].i4), "=&v"(m[11].i4),
                      "=&v"(m[12].i4), "=&v"(m[13].i4), "=&v"(m[14].i4), "=&v"(m[15].i4)
                    : "v"(sb) : "memory");
                // both tag words of every message must equal t
                unsigned int mn = m[0].u[1] < m[0].u[3] ? m[0].u[1] : m[0].u[3];
#pragma unroll
                for (int q = 1; q < 16; ++q) {
                    const unsigned int lo = m[q].u[1] < m[q].u[3] ? m[q].u[1] : m[q].u[3];
                    mn = mn < lo ? mn : lo;
                }
                if (__all(mn == (unsigned int)t)) break;

                if (++rounds > 4096) {
                    // hang-proof fallback: proven agent-atomic semantics (R8 path)
                    for (;;) {
                        unsigned int mn2 = 0xFFFFFFFFu;
#pragma unroll
                        for (int q = 0; q < 16; ++q) {
                            const char* ms = sb + (q >> 1) * 128 + (q & 1) * 16;
                            const unsigned int t0v = __hip_atomic_load(
                                (const unsigned int*)(ms + 4),
                                __ATOMIC_RELAXED, __HIP_MEMORY_SCOPE_AGENT);
                            const unsigned int t1v = __hip_atomic_load(
                                (const unsigned int*)(ms + 12),
                                __ATOMIC_RELAXED, __HIP_MEMORY_SCOPE_AGENT);
                            const unsigned int lo = t0v < t1v ? t0v : t1v;
                            mn2 = mn2 < lo ? mn2 : lo;
                        }
                        if (__all(mn2 == (unsigned int)t)) break;
                    }
#pragma unroll
                    for (int q = 0; q < 16; ++q) {
                        const char* ms = sb + (q >> 1) * 128 + (q & 1) * 16;
                        m[q].u[0] = __hip_atomic_load((const unsigned int*)(ms + 0),
                                        __ATOMIC_RELAXED, __HIP_MEMORY_SCOPE_AGENT);
                        m[q].u[2] = __hip_atomic_load((const unsigned int*)(ms + 8),
                                        __ATOMIC_RELAXED, __HIP_MEMORY_SCOPE_AGENT);
                    }
                    break;
                }
            }
            // ---- h-part MFMAs: zh[kk] from msgs 2kk,2kk+1 (h01 at u[0], h23 at u[2]) ----
#pragma unroll
            for (int kk = 0; kk < 8; ++kk) {
                union { unsigned int u[4]; short8 v; } z;
                z.u[0] = m[2 * kk].u[0];
                z.u[1] = m[2 * kk].u[2];
                z.u[2] = m[2 * kk + 1].u[0];
                z.u[3] = m[2 * kk + 1].u[2];
                a0 = __builtin_amdgcn_mfma_f32_16x16x32_bf16(wf0[kk], z.v, a0, 0, 0, 0);
                a1 = __builtin_amdgcn_mfma_f32_16x16x32_bf16(wf1[kk], z.v, a1, 0, 0, 0);
                a2 = __builtin_amdgcn_mfma_f32_16x16x32_bf16(wf2[kk], z.v, a2, 0, 0, 0);
                a3 = __builtin_amdgcn_mfma_f32_16x16x32_bf16(wf3[kk], z.v, a3, 0, 0, 0);
            }
        }

        // ---- x-part MFMAs ----
#pragma unroll
        for (int kk = 0; kk < 4; ++kk) {
            a0 = __builtin_amdgcn_mfma_f32_16x16x32_bf16(wf0[8 + kk], xf[kk], a0, 0, 0, 0);
            a1 = __builtin_amdgcn_mfma_f32_16x16x32_bf16(wf1[8 + kk], xf[kk], a1, 0, 0, 0);
            a2 = __builtin_amdgcn_mfma_f32_16x16x32_bf16(wf2[8 + kk], xf[kk], a2, 0, 0, 0);
            a3 = __builtin_amdgcn_mfma_f32_16x16x32_bf16(wf3[8 + kk], xf[kk], a3, 0, 0, 0);
        }

        // ---- pointwise cell ----
        float hr[4];
#pragma unroll
        for (int r = 0; r < 4; ++r) {
            const float gi = sig_(a0[r] + bsr[0][r]);
            const float gf = sig_(a1[r] + bsr[1][r]);
            const float gg = tanh_(a2[r] + bsr[2][r]);
            const float go = sig_(a3[r] + bsr[3][r]);
            cr[r] = gf * cr[r] + gi * gg;
            hr[r] = go * tanh_(cr[r]);
        }

        // ---- publish: ONE 16B dual-tag message, no drain, no separate tag store ----
        union { unsigned int u[4]; i32x4 i4; } P;
        __hip_bfloat162 p01(__float2bfloat16(hr[0]), __float2bfloat16(hr[1]));
        __hip_bfloat162 p23(__float2bfloat16(hr[2]), __float2bfloat16(hr[3]));
        P.u[0] = *(unsigned int*)&p01;
        P.u[1] = (unsigned int)(t + 1);
        P.u[2] = *(unsigned int*)&p23;
        P.u[3] = (unsigned int)(t + 1);
        char* dst = hbuf2 + (size_t)(t & 1) * (NEX * 64 * 16) + prod_off;
        asm volatile("global_store_dwordx4 %0, %1, off sc0 sc1"
                     :: "v"(dst), "v"(P.i4) : "memory");

        // ---- outputs (plain cached stores; drained by next step's poll) ----
        const size_t off = (size_t)t * NEX * HDIM + (size_t)ex * HDIM + ub;
        *(float4*)&A[off] = make_float4(hr[0], hr[1], hr[2], hr[3]);
        *(float4*)&C[off] = make_float4(cr[0], cr[1], cr[2], cr[3]);
    }
#undef X_GATHER
}

extern "C" void kernel_launch(void* const* d_in, const int* in_sizes, int n_in,
                              void* d_out, int out_size, void* d_ws, size_t ws_size,
                              hipStream_t stream) {
    const float* X   = (const float*)d_in[0];
    const float* Wih = (const float*)d_in[1];
    const float* Whh = (const float*)d_in[2];
    const float* b   = (const float*)d_in[3];
    float* A = (float*)d_out;
    float* C = A + (size_t)TSTEPS * NEX * HDIM;

    const size_t hbuf_bytes = (size_t)2 * NEX * 64 * 16;                           // 512 KB
    const size_t xp_bytes   = (size_t)TSTEPS * NEX * NIN * sizeof(unsigned short); // 32 MB

    char* hbuf2 = (char*)d_ws;
    unsigned short* xpw = (unsigned short*)((char*)d_ws + hbuf_bytes);
    const bool px = ws_size >= hbuf_bytes + xp_bytes;

    // zero message buffer (tags must start != any expected value; harness poisons 0xAA)
    const int nzero = (int)(hbuf_bytes / 4);
    zero_ws<<<(nzero + 255) / 256, 256, 0, stream>>>((unsigned int*)hbuf2, nzero);
    if (px) pack_x<<<dim3(NEX * 32), dim3(64), 0, stream>>>(X, xpw);

    const unsigned short* xpc = xpw;
    if (px) {
        void* args[] = {(void*)&X, (void*)&Wih, (void*)&Whh, (void*)&b,
                        (void*)&A, (void*)&C, (void*)&hbuf2, (void*)&xpc};
        hipError_t err = hipLaunchCooperativeKernel((const void*)lstm_persist<1>,
                                                    dim3(256), dim3(64), args, 0, stream);
        if (err != hipSuccess) {
            lstm_persist<1><<<dim3(256), dim3(64), 0, stream>>>(X, Wih, Whh, b, A, C, hbuf2, xpc);
        }
    } else {
        void* args[] = {(void*)&X, (void*)&Wih, (void*)&Whh, (void*)&b,
                        (void*)&A, (void*)&C, (void*)&hbuf2, (void*)&xpc};
        hipError_t err = hipLaunchCooperativeKernel((const void*)lstm_persist<0>,
                                                    dim3(256), dim3(64), args, 0, stream);
        if (err != hipSuccess) {
            lstm_persist<0><<<dim3(256), dim3(64), 0, stream>>>(X, Wih, Whh, b, A, C, hbuf2, xpc);
        }
    }
}